// Round 14
// baseline (5031.204 us; speedup 1.0000x reference)
//
#include <hip/hip_runtime.h>
#include <hip/hip_bf16.h>
#include <hip/hip_fp16.h>
#include <math.h>
#include <float.h>

#define BB 16
#define TT 1023
#define CC 2048
#define M_ROWS (BB * TT)   // 16368
#define MP 16384           // padded rows
#define N3 (3 * CC)        // 6144
#define NCH 16             // scan chunks
#define CHL 64             // chunk length

typedef __attribute__((ext_vector_type(8))) short bfrag;   // 8 bf16 (4 VGPRs)
typedef __attribute__((ext_vector_type(4))) float f32x4;   // MFMA C/D frag
typedef __attribute__((ext_vector_type(4))) short short4v;

__device__ __forceinline__ void async16(const void* g, void* l) {
  __builtin_amdgcn_global_load_lds((const __attribute__((address_space(1))) void*)g,
                                   (__attribute__((address_space(3))) void*)l, 16, 0, 0);
}

__device__ __forceinline__ short bfb(float f) {
  __hip_bfloat16 h = __float2bfloat16(f);
  return *reinterpret_cast<short*>(&h);
}

// ---------------- merged prep: build_xm (blocks 0..MP) + weight cast ----------------
__global__ void prep(const float* __restrict__ x, const float* __restrict__ xx,
                     const float* __restrict__ tmix,
                     const float* __restrict__ Wk, const float* __restrict__ Wv,
                     const float* __restrict__ Wr, const float* __restrict__ Wo,
                     __hip_bfloat16* __restrict__ xm,
                     __hip_bfloat16* __restrict__ W3, __hip_bfloat16* __restrict__ WoB) {
  int bid = blockIdx.x;
  if (bid < MP) {
    int m = bid;
    short* orow = (short*)xm + (size_t)m * CC;
    if (m >= M_ROWS) {
      for (int c = threadIdx.x; c < CC / 4; c += 256)
        ((short4v*)orow)[c] = short4v{0, 0, 0, 0};
      return;
    }
    int b = m / TT, t = m - b * TT;
    const float* xrow = x + (size_t)m * CC;
    const float* xprev = (t == 0) ? (xx + (size_t)b * CC) : (xrow - CC);
    for (int c = threadIdx.x; c < CC / 4; c += 256) {
      float4 xv = ((const float4*)xrow)[c];
      float4 pv = ((const float4*)xprev)[c];
      float4 tm = ((const float4*)tmix)[c];
      ((short4v*)orow)[c] = short4v{
          bfb(xv.x * tm.x + pv.x * (1.0f - tm.x)),
          bfb(xv.y * tm.y + pv.y * (1.0f - tm.y)),
          bfb(xv.z * tm.z + pv.z * (1.0f - tm.z)),
          bfb(xv.w * tm.w + pv.w * (1.0f - tm.w))};
    }
  } else {
    size_t i4 = (size_t)(bid - MP) * 256 + threadIdx.x;   // covers CC*CC/4
    size_t i = i4 * 4;
    float4 a = *(const float4*)(Wk + i);
    float4 b = *(const float4*)(Wv + i);
    float4 c = *(const float4*)(Wr + i);
    float4 d = *(const float4*)(Wo + i);
    *(short4v*)((short*)W3 + i)               = short4v{bfb(a.x), bfb(a.y), bfb(a.z), bfb(a.w)};
    *(short4v*)((short*)W3 + i + CC * CC)     = short4v{bfb(b.x), bfb(b.y), bfb(b.z), bfb(b.w)};
    *(short4v*)((short*)W3 + i + 2 * CC * CC) = short4v{bfb(c.x), bfb(c.y), bfb(c.z), bfb(c.w)};
    *(short4v*)((short*)WoB + i)              = short4v{bfb(d.x), bfb(d.y), bfb(d.z), bfb(d.w)};
  }
}

// ---------------- 256x256-tile bf16 MFMA GEMM, BK=32, 2 blocks/CU ----------------
// C[m,n] = sum_k A[m,k]*B[n,k].  8 waves (2M x 4N).
// r14 change: BK 64->32 halves LDS to 64 KB -> 2 blocks/CU (Occupancy 22->44%).
// Rationale: every intra-block schedule variant plateaued with pipes serialized
// at 1 block/CU; m114-style overlap needs FOREIGN waves -- a co-resident block
// whose unsynchronized phases fill our barrier/VM windows.
// LDS: 2 buf x {A,B} regions of 256x32 bf16 (16 KB each) = 64 KB.
// Swizzle: 16B chunk at (row, slot) holds kgrp = slot ^ ((row>>1)&3) (0-conflict).
// Per tile t (buf = t&1):  ph1 { read B + A(mh0); stage ALL 4 units of t+1 into
// buf^1; 16 MFMA; barrier }   ph2 { read A(mh1); 16 MFMA; VM(0); barrier }.
// Ledger: VM(0)+barrier at ph2(t) end -> all t+1 stages landed & visible before
// ph1(t+1) reads buf^1.  Overwrite: buf^1's last readers were at ph2(t-1),
// before its end barrier, before ph1(t)'s stage issue.  Airtight.
// Epilogue (MODE 1): k -> exp(k) fp16; v, r -> raw bf16 (sigmoid kept OUT of the
// epilogue: r13 showed it perturbs main-loop codegen, MfmaUtil -5pts).
template <int MODE>
__global__ __launch_bounds__(512, 4)
void gemm256(const short* __restrict__ A, const short* __restrict__ Bw,
             float* __restrict__ outF, __half* __restrict__ outH,
             __hip_bfloat16* __restrict__ outV, __hip_bfloat16* __restrict__ outR) {
  __shared__ short lds[32768];   // 64 KiB

  const int lane = threadIdx.x & 63, wid = threadIdx.x >> 6;
  const int wr = wid >> 2, wc = wid & 3;

  // XCD-aware swizzle, n-major within chunk (grids are multiples of 8)
  const int nx = gridDim.x;
  const int nwg = nx * gridDim.y;
  const int bid = blockIdx.y * nx + blockIdx.x;
  const int q = nwg >> 3;
  const int swz = (bid & 7) * q + (bid >> 3);
  const int mBase = (swz / nx) * 256;
  const int nBase = (swz % nx) * 256;

  // staging: wave wid covers rows [wid*32, wid*32+32) of the 256-row region
  const int srow = lane >> 2;                                  // 0..15
  const int scol = (((lane & 3) ^ ((lane >> 3) & 3)) * 8);     // inverse-swizzled k-group
  const int stgOff = wid * 1024 + lane * 8;                    // shorts
  const short* aSrcBase = A  + (size_t)(mBase + wid * 32 + srow) * CC + scol;
  const short* bSrcBase = Bw + (size_t)(nBase + wid * 32 + srow) * CC + scol;

  // ds_read: frag lane -> (row = R0 + (l&15), kgrp = l>>4), swizzled slot
  const int ldOff = (lane & 15) * 32 + (((lane >> 4) ^ ((lane >> 1) & 3)) * 8);  // shorts

  f32x4 acc[2][4][4] = {};
  bfrag bq[4];

#define RGNA(buf) ((buf) * 16384)
#define RGNB(buf) (8192 + (buf) * 16384)

#define STG4(buf, tk) do { \
    const short* _sa = aSrcBase + (tk) * 32; \
    short* _da = lds + RGNA(buf) + stgOff; \
    async16(_sa, _da); async16(_sa + (size_t)16 * CC, _da + 512); \
    const short* _sb = bSrcBase + (tk) * 32; \
    short* _db = lds + RGNB(buf) + stgOff; \
    async16(_sb, _db); async16(_sb + (size_t)16 * CC, _db + 512); } while (0)

#define VMN(n) asm volatile("s_waitcnt vmcnt(" #n ")" ::: "memory")

#define MM16(mh, AQ) \
    __builtin_amdgcn_s_setprio(1); \
    _Pragma("unroll") \
    for (int f = 0; f < 4; ++f) \
      _Pragma("unroll") \
      for (int n = 0; n < 4; ++n) \
        acc[mh][f][n] = __builtin_amdgcn_mfma_f32_16x16x32_bf16(AQ[f], bq[n], acc[mh][f][n], 0, 0, 0); \
    __builtin_amdgcn_s_setprio(0);

#define PH1(buf, STAGE) do { \
    bfrag aq[4]; \
    _Pragma("unroll") \
    for (int n = 0; n < 4; ++n) \
      bq[n] = *(const bfrag*)(lds + RGNB(buf) + (wc * 64 + n * 16) * 32 + ldOff); \
    _Pragma("unroll") \
    for (int f = 0; f < 4; ++f) \
      aq[f] = *(const bfrag*)(lds + RGNA(buf) + (wr * 128 + f * 16) * 32 + ldOff); \
    STAGE; \
    MM16(0, aq) \
    __builtin_amdgcn_s_barrier(); } while (0)

#define PH2(buf, WAIT) do { \
    bfrag aq[4]; \
    _Pragma("unroll") \
    for (int f = 0; f < 4; ++f) \
      aq[f] = *(const bfrag*)(lds + RGNA(buf) + (wr * 128 + 64 + f * 16) * 32 + ldOff); \
    MM16(1, aq) \
    WAIT; \
    __builtin_amdgcn_s_barrier(); } while (0)

  // prologue: stage tile0 -> buf0, drain, barrier
  STG4(0, 0);
  VMN(0);
  __builtin_amdgcn_s_barrier();

  // 64 K-tiles of 32; tile t computes buf t&1, ph1 stages t+1 into buf^1
  for (int ti = 0; ti < 62; ti += 2) {
    PH1(0, STG4(1, ti + 1));
    PH2(0, VMN(0));
    PH1(1, STG4(0, ti + 2));
    PH2(1, VMN(0));
  }
  PH1(0, STG4(1, 63));
  PH2(0, VMN(0));
  PH1(1, );          // final tile: no stage
  PH2(1, );          // no VM/barrier needed before C-write (own lgkm only)

#undef PH1
#undef PH2
#undef MM16
#undef VMN
#undef STG4
#undef RGNA
#undef RGNB

  // C-write: col = lane&15, row = (lane>>4)*4 + rr (verified layout)
  // MODE 1: k -> exp(k) fp16; v -> bf16; r -> raw bf16.
#pragma unroll
  for (int mh = 0; mh < 2; ++mh)
#pragma unroll
    for (int f = 0; f < 4; ++f) {
      const int row0 = mBase + wr * 128 + mh * 64 + f * 16 + (lane >> 4) * 4;
      const int col0 = nBase + wc * 64 + (lane & 15);
#pragma unroll
      for (int n = 0; n < 4; ++n) {
        const int col = col0 + n * 16;
#pragma unroll
        for (int rr = 0; rr < 4; ++rr) {
          const int row = row0 + rr;
          if (row < M_ROWS) {
            float val = acc[mh][f][n][rr];
            if constexpr (MODE == 0) {
              outF[(size_t)row * CC + col] = val;
            } else {
              if (col < CC)          outH[(size_t)row * CC + col] = __float2half(expf(val));
              else if (col < 2 * CC) outV[(size_t)row * CC + (col - CC)] = __float2bfloat16(val);
              else                   outR[(size_t)row * CC + (col - 2 * CC)] = __float2bfloat16(val);
            }
          }
        }
      }
    }
}

// ---------------- chunked parallel scan + sigmoid(r)*wkv/wk ----------------
// ek = exp(k) precomputed fp16 by GEMM1 epilogue (renorm-free: ratio invariant;
// state init bb*exp(mm), aa*exp(mm)).  Sigmoid lives here (memory-bound, VALU free).
__global__ __launch_bounds__(1024)
void scan_fuse2(const __half* __restrict__ ek, const __hip_bfloat16* __restrict__ v,
                const __hip_bfloat16* __restrict__ r, const float* __restrict__ aa,
                const float* __restrict__ bb, const float* __restrict__ mm,
                const float* __restrict__ tdec, const float* __restrict__ tfir,
                __hip_bfloat16* __restrict__ rwkv) {
  __shared__ float sBk[NCH][64], sBkv[NCH][64], sSk[NCH][64], sSkv[NCH][64];

  const int lane = threadIdx.x & 63, wid = threadIdx.x >> 6;
  const int c = blockIdx.x * 64 + lane;
  const int b = blockIdx.y;
  const int i = b * CC + c;

  const float dexp = expf(tdec[c]);
  const float d    = expf(-dexp);
  const float ef   = expf(tfir[c]);

  const int t0 = wid * CHL;
  const int t1 = (t0 + CHL < TT) ? t0 + CHL : TT;
  const size_t base = (size_t)b * TT * CC + c;

  if (wid < NCH - 1) {
    float Bk = 0.0f, Bkv = 0.0f;
    size_t off = base + (size_t)t0 * CC;
#pragma unroll 4
    for (int t = t0; t < t1; ++t, off += CC) {
      float kk = __half2float(ek[off]);
      float kv = kk * __bfloat162float(v[off]);
      Bk = d * Bk + kk;
      Bkv = d * Bkv + kv;
    }
    sBk[wid][lane] = Bk;
    sBkv[wid][lane] = Bkv;
  }
  __syncthreads();

  if (wid == 0) {
    const float d64 = expf(-dexp * (float)CHL);
    const float sc = expf(mm[i]);
    float S = bb[i] * sc, Sv = aa[i] * sc;
#pragma unroll
    for (int j = 0; j < NCH; ++j) {
      sSk[j][lane] = S;
      sSkv[j][lane] = Sv;
      if (j < NCH - 1) {
        S = d64 * S + sBk[j][lane];
        Sv = d64 * Sv + sBkv[j][lane];
      }
    }
  }
  __syncthreads();

  float S = sSk[wid][lane], Sv = sSkv[wid][lane];
  size_t off = base + (size_t)t0 * CC;
#pragma unroll 4
  for (int t = t0; t < t1; ++t, off += CC) {
    float kk = __half2float(ek[off]);
    float vv = __bfloat162float(v[off]);
    float rv = __bfloat162float(r[off]);
    float kv = kk * vv;
    float wk = ef * kk + S;
    float wkv = ef * kv + Sv;
    S = d * S + kk;
    Sv = d * Sv + kv;
    float ratio = wkv / wk;
    if (isnan(ratio)) ratio = 0.0f;
    else if (isinf(ratio)) ratio = ratio > 0.0f ? FLT_MAX : -FLT_MAX;
    float sig = 1.0f / (1.0f + expf(-rv));
    rwkv[off] = __float2bfloat16(sig * ratio);
  }
}

extern "C" void kernel_launch(void* const* d_in, const int* in_sizes, int n_in,
                              void* d_out, int out_size, void* d_ws, size_t ws_size,
                              hipStream_t stream) {
  const float* x    = (const float*)d_in[0];
  const float* tdec = (const float*)d_in[1];
  const float* tfir = (const float*)d_in[2];
  const float* tmix = (const float*)d_in[3];
  const float* Wk   = (const float*)d_in[4];
  const float* Wv   = (const float*)d_in[5];
  const float* Wr   = (const float*)d_in[6];
  const float* Wo   = (const float*)d_in[7];
  const float* xx   = (const float*)d_in[8];
  const float* aa   = (const float*)d_in[9];
  const float* bb   = (const float*)d_in[10];
  const float* mm   = (const float*)d_in[11];

  char* ws = (char*)d_ws;
  size_t o = 0;
  __hip_bfloat16* W3  = (__hip_bfloat16*)(ws + o); o += (size_t)N3 * CC * 2;
  __hip_bfloat16* WoB = (__hip_bfloat16*)(ws + o); o += (size_t)CC * CC * 2;
  __hip_bfloat16* xmB = (__hip_bfloat16*)(ws + o); o += (size_t)MP * CC * 2;
  __hip_bfloat16* vB  = (__hip_bfloat16*)(ws + o); o += (size_t)MP * CC * 2;
  __hip_bfloat16* rB  = (__hip_bfloat16*)(ws + o); o += (size_t)MP * CC * 2;

  __half* ekH = (__half*)d_out;        // exp(k) fp16 lives in d_out until GEMM2
  __hip_bfloat16* rwkvB = xmB;         // rwkv reuses xm buffer (xm dead after GEMM1)

  prep<<<MP + CC * CC / 1024, 256, 0, stream>>>(x, xx, tmix, Wk, Wv, Wr, Wo,
                                                xmB, W3, WoB);
  gemm256<1><<<dim3(N3 / 256, MP / 256), 512, 0, stream>>>(
      (const short*)xmB, (const short*)W3, nullptr, ekH, vB, rB);
  scan_fuse2<<<dim3(CC / 64, BB), 1024, 0, stream>>>(ekH, vB, rB, aa, bb, mm,
                                                     tdec, tfir, rwkvB);
  gemm256<0><<<dim3(CC / 256, MP / 256), 512, 0, stream>>>(
      (const short*)rwkvB, (const short*)WoB, (float*)d_out, nullptr, nullptr, nullptr);
}

// Round 15
// 724.739 us; speedup vs baseline: 6.9421x; 6.9421x over previous
//
#include <hip/hip_runtime.h>
#include <hip/hip_bf16.h>
#include <hip/hip_fp16.h>
#include <math.h>
#include <float.h>

#define BB 16
#define TT 1023
#define CC 2048
#define M_ROWS (BB * TT)   // 16368
#define MP 16384           // padded rows
#define N3 (3 * CC)        // 6144
#define NCH 16             // scan chunks
#define CHL 64             // chunk length

typedef __attribute__((ext_vector_type(8))) short bfrag;   // 8 bf16 (4 VGPRs)
typedef __attribute__((ext_vector_type(4))) float f32x4;   // MFMA C/D frag
typedef __attribute__((ext_vector_type(4))) short short4v;

__device__ __forceinline__ void async16(const void* g, void* l) {
  __builtin_amdgcn_global_load_lds((const __attribute__((address_space(1))) void*)g,
                                   (__attribute__((address_space(3))) void*)l, 16, 0, 0);
}

__device__ __forceinline__ short bfb(float f) {
  __hip_bfloat16 h = __float2bfloat16(f);
  return *reinterpret_cast<short*>(&h);
}

// ---------------- merged prep: build_xm (blocks 0..MP) + weight cast ----------------
__global__ void prep(const float* __restrict__ x, const float* __restrict__ xx,
                     const float* __restrict__ tmix,
                     const float* __restrict__ Wk, const float* __restrict__ Wv,
                     const float* __restrict__ Wr, const float* __restrict__ Wo,
                     __hip_bfloat16* __restrict__ xm,
                     __hip_bfloat16* __restrict__ W3, __hip_bfloat16* __restrict__ WoB) {
  int bid = blockIdx.x;
  if (bid < MP) {
    int m = bid;
    short* orow = (short*)xm + (size_t)m * CC;
    if (m >= M_ROWS) {
      for (int c = threadIdx.x; c < CC / 4; c += 256)
        ((short4v*)orow)[c] = short4v{0, 0, 0, 0};
      return;
    }
    int b = m / TT, t = m - b * TT;
    const float* xrow = x + (size_t)m * CC;
    const float* xprev = (t == 0) ? (xx + (size_t)b * CC) : (xrow - CC);
    for (int c = threadIdx.x; c < CC / 4; c += 256) {
      float4 xv = ((const float4*)xrow)[c];
      float4 pv = ((const float4*)xprev)[c];
      float4 tm = ((const float4*)tmix)[c];
      ((short4v*)orow)[c] = short4v{
          bfb(xv.x * tm.x + pv.x * (1.0f - tm.x)),
          bfb(xv.y * tm.y + pv.y * (1.0f - tm.y)),
          bfb(xv.z * tm.z + pv.z * (1.0f - tm.z)),
          bfb(xv.w * tm.w + pv.w * (1.0f - tm.w))};
    }
  } else {
    size_t i4 = (size_t)(bid - MP) * 256 + threadIdx.x;   // covers CC*CC/4
    size_t i = i4 * 4;
    float4 a = *(const float4*)(Wk + i);
    float4 b = *(const float4*)(Wv + i);
    float4 c = *(const float4*)(Wr + i);
    float4 d = *(const float4*)(Wo + i);
    *(short4v*)((short*)W3 + i)               = short4v{bfb(a.x), bfb(a.y), bfb(a.z), bfb(a.w)};
    *(short4v*)((short*)W3 + i + CC * CC)     = short4v{bfb(b.x), bfb(b.y), bfb(b.z), bfb(b.w)};
    *(short4v*)((short*)W3 + i + 2 * CC * CC) = short4v{bfb(c.x), bfb(c.y), bfb(c.z), bfb(c.w)};
    *(short4v*)((short*)WoB + i)              = short4v{bfb(d.x), bfb(d.y), bfb(d.z), bfb(d.w)};
  }
}

// ---------------- 256x256-tile bf16 MFMA GEMM, BK=32, 2 blocks/CU ----------------
// C[m,n] = sum_k A[m,k]*B[n,k].  8 waves (2M x 4N).
// BK=32 halves LDS to 64 KB so TWO blocks fit per CU.  Rationale: every
// intra-block schedule variant plateaued with LDS and MFMA pipes serialized at
// 1 block/CU; m114-style overlap needs FOREIGN waves — a co-resident block
// whose unsynchronized phases fill our barrier/VM windows.
// r15 fix vs r14: __launch_bounds__(512, 2) — NOT (512,4).  r14's (512,4) made
// the compiler clamp VGPR to 64, spilling the 128-reg accumulator to scratch
// (18 GB HBM traffic, MfmaUtil 4.7%).  With (512,2) the kernel allocates ~112
// VGPR; 4 waves x 112 = 448 <= 512/SIMD pool (m69), so 2 blocks/CU co-reside
// from ACTUAL usage, no clamp.
// LDS: 2 buf x {A,B} regions of 256x32 bf16 (16 KB each) = 64 KB.
// Swizzle: 16B chunk at (row, slot) holds kgrp = slot ^ ((row>>1)&3) (0-conflict).
// Per tile t (buf = t&1):  ph1 { read B + A(mh0); stage ALL 4 units of t+1 into
// buf^1; 16 MFMA; barrier }   ph2 { read A(mh1); 16 MFMA; VM(0); barrier }.
// Ledger: VM(0)+barrier at ph2(t) end -> all t+1 stages landed & visible before
// ph1(t+1) reads buf^1.  Overwrite: buf^1's last readers were at ph2(t-1),
// before its end barrier, before ph1(t)'s stage issue.  Airtight.
// Epilogue (MODE 1): k -> exp(k) fp16; v, r -> raw bf16 (sigmoid kept OUT:
// r13 showed epilogue VALU perturbs main-loop codegen, MfmaUtil -5pts).
template <int MODE>
__global__ __launch_bounds__(512, 2)
void gemm256(const short* __restrict__ A, const short* __restrict__ Bw,
             float* __restrict__ outF, __half* __restrict__ outH,
             __hip_bfloat16* __restrict__ outV, __hip_bfloat16* __restrict__ outR) {
  __shared__ short lds[32768];   // 64 KiB

  const int lane = threadIdx.x & 63, wid = threadIdx.x >> 6;
  const int wr = wid >> 2, wc = wid & 3;

  // XCD-aware swizzle, n-major within chunk (grids are multiples of 8)
  const int nx = gridDim.x;
  const int nwg = nx * gridDim.y;
  const int bid = blockIdx.y * nx + blockIdx.x;
  const int q = nwg >> 3;
  const int swz = (bid & 7) * q + (bid >> 3);
  const int mBase = (swz / nx) * 256;
  const int nBase = (swz % nx) * 256;

  // staging: wave wid covers rows [wid*32, wid*32+32) of the 256-row region
  const int srow = lane >> 2;                                  // 0..15
  const int scol = (((lane & 3) ^ ((lane >> 3) & 3)) * 8);     // inverse-swizzled k-group
  const int stgOff = wid * 1024 + lane * 8;                    // shorts
  const short* aSrcBase = A  + (size_t)(mBase + wid * 32 + srow) * CC + scol;
  const short* bSrcBase = Bw + (size_t)(nBase + wid * 32 + srow) * CC + scol;

  // ds_read: frag lane -> (row = R0 + (l&15), kgrp = l>>4), swizzled slot
  const int ldOff = (lane & 15) * 32 + (((lane >> 4) ^ ((lane >> 1) & 3)) * 8);  // shorts

  f32x4 acc[2][4][4] = {};
  bfrag bq[4];

#define RGNA(buf) ((buf) * 16384)
#define RGNB(buf) (8192 + (buf) * 16384)

#define STG4(buf, tk) do { \
    const short* _sa = aSrcBase + (tk) * 32; \
    short* _da = lds + RGNA(buf) + stgOff; \
    async16(_sa, _da); async16(_sa + (size_t)16 * CC, _da + 512); \
    const short* _sb = bSrcBase + (tk) * 32; \
    short* _db = lds + RGNB(buf) + stgOff; \
    async16(_sb, _db); async16(_sb + (size_t)16 * CC, _db + 512); } while (0)

#define VMN(n) asm volatile("s_waitcnt vmcnt(" #n ")" ::: "memory")

#define MM16(mh, AQ) \
    __builtin_amdgcn_s_setprio(1); \
    _Pragma("unroll") \
    for (int f = 0; f < 4; ++f) \
      _Pragma("unroll") \
      for (int n = 0; n < 4; ++n) \
        acc[mh][f][n] = __builtin_amdgcn_mfma_f32_16x16x32_bf16(AQ[f], bq[n], acc[mh][f][n], 0, 0, 0); \
    __builtin_amdgcn_s_setprio(0);

#define PH1(buf, STAGE) do { \
    bfrag aq[4]; \
    _Pragma("unroll") \
    for (int n = 0; n < 4; ++n) \
      bq[n] = *(const bfrag*)(lds + RGNB(buf) + (wc * 64 + n * 16) * 32 + ldOff); \
    _Pragma("unroll") \
    for (int f = 0; f < 4; ++f) \
      aq[f] = *(const bfrag*)(lds + RGNA(buf) + (wr * 128 + f * 16) * 32 + ldOff); \
    STAGE; \
    MM16(0, aq) \
    __builtin_amdgcn_s_barrier(); } while (0)

#define PH2(buf, WAIT) do { \
    bfrag aq[4]; \
    _Pragma("unroll") \
    for (int f = 0; f < 4; ++f) \
      aq[f] = *(const bfrag*)(lds + RGNA(buf) + (wr * 128 + 64 + f * 16) * 32 + ldOff); \
    MM16(1, aq) \
    WAIT; \
    __builtin_amdgcn_s_barrier(); } while (0)

  // prologue: stage tile0 -> buf0, drain, barrier
  STG4(0, 0);
  VMN(0);
  __builtin_amdgcn_s_barrier();

  // 64 K-tiles of 32; tile t computes buf t&1, ph1 stages t+1 into buf^1
  for (int ti = 0; ti < 62; ti += 2) {
    PH1(0, STG4(1, ti + 1));
    PH2(0, VMN(0));
    PH1(1, STG4(0, ti + 2));
    PH2(1, VMN(0));
  }
  PH1(0, STG4(1, 63));
  PH2(0, VMN(0));
  PH1(1, );          // final tile: no stage
  PH2(1, );          // no VM/barrier needed before C-write (own lgkm only)

#undef PH1
#undef PH2
#undef MM16
#undef VMN
#undef STG4
#undef RGNA
#undef RGNB

  // C-write: col = lane&15, row = (lane>>4)*4 + rr (verified layout)
  // MODE 1: k -> exp(k) fp16; v -> bf16; r -> raw bf16.
#pragma unroll
  for (int mh = 0; mh < 2; ++mh)
#pragma unroll
    for (int f = 0; f < 4; ++f) {
      const int row0 = mBase + wr * 128 + mh * 64 + f * 16 + (lane >> 4) * 4;
      const int col0 = nBase + wc * 64 + (lane & 15);
#pragma unroll
      for (int n = 0; n < 4; ++n) {
        const int col = col0 + n * 16;
#pragma unroll
        for (int rr = 0; rr < 4; ++rr) {
          const int row = row0 + rr;
          if (row < M_ROWS) {
            float val = acc[mh][f][n][rr];
            if constexpr (MODE == 0) {
              outF[(size_t)row * CC + col] = val;
            } else {
              if (col < CC)          outH[(size_t)row * CC + col] = __float2half(expf(val));
              else if (col < 2 * CC) outV[(size_t)row * CC + (col - CC)] = __float2bfloat16(val);
              else                   outR[(size_t)row * CC + (col - 2 * CC)] = __float2bfloat16(val);
            }
          }
        }
      }
    }
}

// ---------------- chunked parallel scan + sigmoid(r)*wkv/wk ----------------
// ek = exp(k) precomputed fp16 by GEMM1 epilogue (renorm-free: ratio invariant;
// state init bb*exp(mm), aa*exp(mm)).  Sigmoid lives here (memory-bound, VALU free).
__global__ __launch_bounds__(1024)
void scan_fuse2(const __half* __restrict__ ek, const __hip_bfloat16* __restrict__ v,
                const __hip_bfloat16* __restrict__ r, const float* __restrict__ aa,
                const float* __restrict__ bb, const float* __restrict__ mm,
                const float* __restrict__ tdec, const float* __restrict__ tfir,
                __hip_bfloat16* __restrict__ rwkv) {
  __shared__ float sBk[NCH][64], sBkv[NCH][64], sSk[NCH][64], sSkv[NCH][64];

  const int lane = threadIdx.x & 63, wid = threadIdx.x >> 6;
  const int c = blockIdx.x * 64 + lane;
  const int b = blockIdx.y;
  const int i = b * CC + c;

  const float dexp = expf(tdec[c]);
  const float d    = expf(-dexp);
  const float ef   = expf(tfir[c]);

  const int t0 = wid * CHL;
  const int t1 = (t0 + CHL < TT) ? t0 + CHL : TT;
  const size_t base = (size_t)b * TT * CC + c;

  if (wid < NCH - 1) {
    float Bk = 0.0f, Bkv = 0.0f;
    size_t off = base + (size_t)t0 * CC;
#pragma unroll 4
    for (int t = t0; t < t1; ++t, off += CC) {
      float kk = __half2float(ek[off]);
      float kv = kk * __bfloat162float(v[off]);
      Bk = d * Bk + kk;
      Bkv = d * Bkv + kv;
    }
    sBk[wid][lane] = Bk;
    sBkv[wid][lane] = Bkv;
  }
  __syncthreads();

  if (wid == 0) {
    const float d64 = expf(-dexp * (float)CHL);
    const float sc = expf(mm[i]);
    float S = bb[i] * sc, Sv = aa[i] * sc;
#pragma unroll
    for (int j = 0; j < NCH; ++j) {
      sSk[j][lane] = S;
      sSkv[j][lane] = Sv;
      if (j < NCH - 1) {
        S = d64 * S + sBk[j][lane];
        Sv = d64 * Sv + sBkv[j][lane];
      }
    }
  }
  __syncthreads();

  float S = sSk[wid][lane], Sv = sSkv[wid][lane];
  size_t off = base + (size_t)t0 * CC;
#pragma unroll 4
  for (int t = t0; t < t1; ++t, off += CC) {
    float kk = __half2float(ek[off]);
    float vv = __bfloat162float(v[off]);
    float rv = __bfloat162float(r[off]);
    float kv = kk * vv;
    float wk = ef * kk + S;
    float wkv = ef * kv + Sv;
    S = d * S + kk;
    Sv = d * Sv + kv;
    float ratio = wkv / wk;
    if (isnan(ratio)) ratio = 0.0f;
    else if (isinf(ratio)) ratio = ratio > 0.0f ? FLT_MAX : -FLT_MAX;
    float sig = 1.0f / (1.0f + expf(-rv));
    rwkv[off] = __float2bfloat16(sig * ratio);
  }
}

extern "C" void kernel_launch(void* const* d_in, const int* in_sizes, int n_in,
                              void* d_out, int out_size, void* d_ws, size_t ws_size,
                              hipStream_t stream) {
  const float* x    = (const float*)d_in[0];
  const float* tdec = (const float*)d_in[1];
  const float* tfir = (const float*)d_in[2];
  const float* tmix = (const float*)d_in[3];
  const float* Wk   = (const float*)d_in[4];
  const float* Wv   = (const float*)d_in[5];
  const float* Wr   = (const float*)d_in[6];
  const float* Wo   = (const float*)d_in[7];
  const float* xx   = (const float*)d_in[8];
  const float* aa   = (const float*)d_in[9];
  const float* bb   = (const float*)d_in[10];
  const float* mm   = (const float*)d_in[11];

  char* ws = (char*)d_ws;
  size_t o = 0;
  __hip_bfloat16* W3  = (__hip_bfloat16*)(ws + o); o += (size_t)N3 * CC * 2;
  __hip_bfloat16* WoB = (__hip_bfloat16*)(ws + o); o += (size_t)CC * CC * 2;
  __hip_bfloat16* xmB = (__hip_bfloat16*)(ws + o); o += (size_t)MP * CC * 2;
  __hip_bfloat16* vB  = (__hip_bfloat16*)(ws + o); o += (size_t)MP * CC * 2;
  __hip_bfloat16* rB  = (__hip_bfloat16*)(ws + o); o += (size_t)MP * CC * 2;

  __half* ekH = (__half*)d_out;        // exp(k) fp16 lives in d_out until GEMM2
  __hip_bfloat16* rwkvB = xmB;         // rwkv reuses xm buffer (xm dead after GEMM1)

  prep<<<MP + CC * CC / 1024, 256, 0, stream>>>(x, xx, tmix, Wk, Wv, Wr, Wo,
                                                xmB, W3, WoB);
  gemm256<1><<<dim3(N3 / 256, MP / 256), 512, 0, stream>>>(
      (const short*)xmB, (const short*)W3, nullptr, ekH, vB, rB);
  scan_fuse2<<<dim3(CC / 64, BB), 1024, 0, stream>>>(ekH, vB, rB, aa, bb, mm,
                                                     tdec, tfir, rwkvB);
  gemm256<0><<<dim3(CC / 256, MP / 256), 512, 0, stream>>>(
      (const short*)rwkvB, (const short*)WoB, (float*)d_out, nullptr, nullptr, nullptr);
}

// Round 16
// 675.292 us; speedup vs baseline: 7.4504x; 1.0732x over previous
//
#include <hip/hip_runtime.h>
#include <hip/hip_bf16.h>
#include <hip/hip_fp16.h>
#include <math.h>
#include <float.h>

#define BB 16
#define TT 1023
#define CC 2048
#define M_ROWS (BB * TT)   // 16368
#define MP 16384           // padded rows
#define N3 (3 * CC)        // 6144
#define NCH 16             // scan chunks
#define CHL 64             // chunk length

typedef __attribute__((ext_vector_type(8))) short bfrag;   // 8 bf16 (4 VGPRs)
typedef __attribute__((ext_vector_type(4))) float f32x4;   // MFMA C/D frag
typedef __attribute__((ext_vector_type(4))) short short4v;

__device__ __forceinline__ void async16(const void* g, void* l) {
  __builtin_amdgcn_global_load_lds((const __attribute__((address_space(1))) void*)g,
                                   (__attribute__((address_space(3))) void*)l, 16, 0, 0);
}

__device__ __forceinline__ short bfb(float f) {
  __hip_bfloat16 h = __float2bfloat16(f);
  return *reinterpret_cast<short*>(&h);
}

// ---------------- merged prep: build_xm (blocks 0..MP) + weight cast ----------------
__global__ void prep(const float* __restrict__ x, const float* __restrict__ xx,
                     const float* __restrict__ tmix,
                     const float* __restrict__ Wk, const float* __restrict__ Wv,
                     const float* __restrict__ Wr, const float* __restrict__ Wo,
                     __hip_bfloat16* __restrict__ xm,
                     __hip_bfloat16* __restrict__ W3, __hip_bfloat16* __restrict__ WoB) {
  int bid = blockIdx.x;
  if (bid < MP) {
    int m = bid;
    short* orow = (short*)xm + (size_t)m * CC;
    if (m >= M_ROWS) {
      for (int c = threadIdx.x; c < CC / 4; c += 256)
        ((short4v*)orow)[c] = short4v{0, 0, 0, 0};
      return;
    }
    int b = m / TT, t = m - b * TT;
    const float* xrow = x + (size_t)m * CC;
    const float* xprev = (t == 0) ? (xx + (size_t)b * CC) : (xrow - CC);
    for (int c = threadIdx.x; c < CC / 4; c += 256) {
      float4 xv = ((const float4*)xrow)[c];
      float4 pv = ((const float4*)xprev)[c];
      float4 tm = ((const float4*)tmix)[c];
      ((short4v*)orow)[c] = short4v{
          bfb(xv.x * tm.x + pv.x * (1.0f - tm.x)),
          bfb(xv.y * tm.y + pv.y * (1.0f - tm.y)),
          bfb(xv.z * tm.z + pv.z * (1.0f - tm.z)),
          bfb(xv.w * tm.w + pv.w * (1.0f - tm.w))};
    }
  } else {
    size_t i4 = (size_t)(bid - MP) * 256 + threadIdx.x;   // covers CC*CC/4
    size_t i = i4 * 4;
    float4 a = *(const float4*)(Wk + i);
    float4 b = *(const float4*)(Wv + i);
    float4 c = *(const float4*)(Wr + i);
    float4 d = *(const float4*)(Wo + i);
    *(short4v*)((short*)W3 + i)               = short4v{bfb(a.x), bfb(a.y), bfb(a.z), bfb(a.w)};
    *(short4v*)((short*)W3 + i + CC * CC)     = short4v{bfb(b.x), bfb(b.y), bfb(b.z), bfb(b.w)};
    *(short4v*)((short*)W3 + i + 2 * CC * CC) = short4v{bfb(c.x), bfb(c.y), bfb(c.z), bfb(c.w)};
    *(short4v*)((short*)WoB + i)              = short4v{bfb(d.x), bfb(d.y), bfb(d.z), bfb(d.w)};
  }
}

// ---------------- 256x256-tile bf16 MFMA GEMM, 16 waves, 64x64 acc ----------------
// C[m,n] = sum_k A[m,k]*B[n,k].  1024 threads = 16 waves (4M x 4N), per-wave
// output 64x64 -> acc = 64 f32 (AGPR).  Why: r15 showed the occupancy wall is
// the UNIFIED VGPR+AGPR budget (112 VGPR + 128 AGPR acc ~ 240/wave -> only 2
// waves/SIMD).  Halving acc to 64 + ~55 VGPR fits 128 total -> 4 waves/SIMD
// (launch_bounds(1024,4) sets that budget; unlike r14, acc=64 fits with ~60
// VGPR headroom, no spill expected).  Bet: 2x wave parallelism per SIMD
// finally overlaps the LDS-read and MFMA pipes (measured fully serialized at
// 2 waves/SIMD across 8 schedule variants).
// LDS: 2 buf x 2 kh x {A,B} regions of 256x32 bf16 (16 KB) = 128 KB.
// Swizzle: 16B chunk at (row, slot) holds kgrp = slot ^ ((row>>1)&3)
// (0-conflict; staging/read XOR algebra unchanged: wave row offsets are
// multiples of 16 -> (row>>1)&3 depends only on lane bits, as before).
// Schedule: 4 phases per 2 K-tiles, ONE barrier per phase:
//   PH(buf,kh) = { read 4 B frags + 4 A frags; stage A+B unit (2 async16);
//                  16 MFMA; [VMN(2) on ph2/ph4]; s_barrier }
// Ledger (units a/b per phase, 2 loads each; s1..s8 = a11,b11,a00,b00,a01,
// b01,a10,b10): ph2-VMN(2) retires {prev a10,b10, a11,b11} -> covers ph3
// (buf1.K0) and ph4 (buf1.K1).  ph4-VMN(2) retires {a00,b00,a01,b01} ->
// covers next ph1/ph2 (buf0).  Prologue: 6 units buf0+buf1.K0, VMN(2)
// retires buf0 (4 oldest of 6).  Epilogue: e2-VMN(2) retires buf1.K0;
// e3-VMN(0) retires buf1.K1.  Airtight.
// Epilogue (MODE 1): k -> exp(k) fp16; v, r -> raw bf16.
template <int MODE>
__global__ __launch_bounds__(1024, 4)
void gemm256(const short* __restrict__ A, const short* __restrict__ Bw,
             float* __restrict__ outF, __half* __restrict__ outH,
             __hip_bfloat16* __restrict__ outV, __hip_bfloat16* __restrict__ outR) {
  __shared__ short lds[65536];   // 128 KiB

  const int lane = threadIdx.x & 63, wid = threadIdx.x >> 6;   // wid 0..15
  const int wr = wid >> 2, wc = wid & 3;                        // 4M x 4N

  // XCD-aware swizzle, n-major within chunk (grids are multiples of 8)
  const int nx = gridDim.x;
  const int nwg = nx * gridDim.y;
  const int bid = blockIdx.y * nx + blockIdx.x;
  const int q = nwg >> 3;
  const int swz = (bid & 7) * q + (bid >> 3);
  const int mBase = (swz / nx) * 256;
  const int nBase = (swz % nx) * 256;

  // staging: wave wid covers rows [wid*16, wid*16+16); 1 async16/thread/region
  const int srow = lane >> 2;                                  // 0..15
  const int scol = (((lane & 3) ^ ((lane >> 3) & 3)) * 8);     // inverse-swizzled k-group
  const int stgOff = wid * 512 + lane * 8;                     // shorts
  const short* aSrcBase = A  + (size_t)(mBase + wid * 16 + srow) * CC + scol;
  const short* bSrcBase = Bw + (size_t)(nBase + wid * 16 + srow) * CC + scol;

  // ds_read: frag lane -> (row = R0 + (l&15), kgrp = l>>4), swizzled slot
  const int ldOff = (lane & 15) * 32 + (((lane >> 4) ^ ((lane >> 1) & 3)) * 8);  // shorts

  f32x4 acc[4][4] = {};   // 64 f32 -> AGPRs

#define RGNA(buf, kh) ((buf) * 32768 + (kh) * 8192)
#define RGNB(buf, kh) (16384 + (buf) * 32768 + (kh) * 8192)

#define STG_A(buf, kh, tk) \
    async16(aSrcBase + ((tk) * 64 + (kh) * 32), lds + RGNA(buf, kh) + stgOff);

#define STG_B(buf, kh, tk) \
    async16(bSrcBase + ((tk) * 64 + (kh) * 32), lds + RGNB(buf, kh) + stgOff);

#define VMN(n) asm volatile("s_waitcnt vmcnt(" #n ")" ::: "memory")

// phase: reads ; stage ; MFMA ; wait ; ONE barrier
#define PH(buf, kh, STAGE, WAIT) do { \
    bfrag aq[4], bq[4]; \
    _Pragma("unroll") \
    for (int n = 0; n < 4; ++n) \
      bq[n] = *(const bfrag*)(lds + RGNB(buf, kh) + (wc * 64 + n * 16) * 32 + ldOff); \
    _Pragma("unroll") \
    for (int f = 0; f < 4; ++f) \
      aq[f] = *(const bfrag*)(lds + RGNA(buf, kh) + (wr * 64 + f * 16) * 32 + ldOff); \
    STAGE; \
    __builtin_amdgcn_s_setprio(1); \
    _Pragma("unroll") \
    for (int f = 0; f < 4; ++f) \
      _Pragma("unroll") \
      for (int n = 0; n < 4; ++n) \
        acc[f][n] = __builtin_amdgcn_mfma_f32_16x16x32_bf16(aq[f], bq[n], acc[f][n], 0, 0, 0); \
    __builtin_amdgcn_s_setprio(0); \
    WAIT; \
    __builtin_amdgcn_s_barrier(); } while (0)

  // prologue: buf0 (both kh) + buf1.K0 = 6 units; VMN(2) retires buf0's 4.
  STG_A(0, 0, 0) STG_B(0, 0, 0)
  STG_A(0, 1, 0) STG_B(0, 1, 0)
  STG_A(1, 0, 1) STG_B(1, 0, 1)
  VMN(2);
  __builtin_amdgcn_s_barrier();

  // 32 K-tiles of 64, consumed in pairs (buf0 then buf1), 4 phases/pair.
  for (int ti = 0; ti < 30; ti += 2) {
    PH(0, 0, STG_A(1, 1, ti + 1) STG_B(1, 1, ti + 1), );
    PH(0, 1, STG_A(0, 0, ti + 2) STG_B(0, 0, ti + 2), VMN(2));
    PH(1, 0, STG_A(0, 1, ti + 2) STG_B(0, 1, ti + 2), );
    PH(1, 1, STG_A(1, 0, ti + 3) STG_B(1, 0, ti + 3), VMN(2));
  }
  // epilogue: tile30 in buf0 (staged), tile31 in buf1 (K0 staged; K1 here).
  PH(0, 0, STG_A(1, 1, 31) STG_B(1, 1, 31), );
  PH(0, 1, , VMN(2));   // retires prev a10,b10 (buf1.K0) -> e3 reads
  PH(1, 0, , VMN(0));   // retires a11,b11 (buf1.K1) -> e4 reads
  PH(1, 1, , );

#undef PH
#undef VMN
#undef STG_A
#undef STG_B
#undef RGNA
#undef RGNB

  // C-write: col = lane&15, row = (lane>>4)*4 + rr (verified layout)
  // MODE 1: k -> exp(k) fp16; v -> bf16; r -> raw bf16.
#pragma unroll
  for (int f = 0; f < 4; ++f) {
    const int row0 = mBase + wr * 64 + f * 16 + (lane >> 4) * 4;
    const int col0 = nBase + wc * 64 + (lane & 15);
#pragma unroll
    for (int n = 0; n < 4; ++n) {
      const int col = col0 + n * 16;
#pragma unroll
      for (int rr = 0; rr < 4; ++rr) {
        const int row = row0 + rr;
        if (row < M_ROWS) {
          float val = acc[f][n][rr];
          if constexpr (MODE == 0) {
            outF[(size_t)row * CC + col] = val;
          } else {
            if (col < CC)          outH[(size_t)row * CC + col] = __float2half(expf(val));
            else if (col < 2 * CC) outV[(size_t)row * CC + (col - CC)] = __float2bfloat16(val);
            else                   outR[(size_t)row * CC + (col - 2 * CC)] = __float2bfloat16(val);
          }
        }
      }
    }
  }
}

// ---------------- chunked parallel scan + sigmoid(r)*wkv/wk ----------------
// ek = exp(k) precomputed fp16 by GEMM1 epilogue (renorm-free: ratio invariant;
// state init bb*exp(mm), aa*exp(mm)).  Sigmoid lives here (memory-bound, VALU free).
__global__ __launch_bounds__(1024)
void scan_fuse2(const __half* __restrict__ ek, const __hip_bfloat16* __restrict__ v,
                const __hip_bfloat16* __restrict__ r, const float* __restrict__ aa,
                const float* __restrict__ bb, const float* __restrict__ mm,
                const float* __restrict__ tdec, const float* __restrict__ tfir,
                __hip_bfloat16* __restrict__ rwkv) {
  __shared__ float sBk[NCH][64], sBkv[NCH][64], sSk[NCH][64], sSkv[NCH][64];

  const int lane = threadIdx.x & 63, wid = threadIdx.x >> 6;
  const int c = blockIdx.x * 64 + lane;
  const int b = blockIdx.y;
  const int i = b * CC + c;

  const float dexp = expf(tdec[c]);
  const float d    = expf(-dexp);
  const float ef   = expf(tfir[c]);

  const int t0 = wid * CHL;
  const int t1 = (t0 + CHL < TT) ? t0 + CHL : TT;
  const size_t base = (size_t)b * TT * CC + c;

  if (wid < NCH - 1) {
    float Bk = 0.0f, Bkv = 0.0f;
    size_t off = base + (size_t)t0 * CC;
#pragma unroll 4
    for (int t = t0; t < t1; ++t, off += CC) {
      float kk = __half2float(ek[off]);
      float kv = kk * __bfloat162float(v[off]);
      Bk = d * Bk + kk;
      Bkv = d * Bkv + kv;
    }
    sBk[wid][lane] = Bk;
    sBkv[wid][lane] = Bkv;
  }
  __syncthreads();

  if (wid == 0) {
    const float d64 = expf(-dexp * (float)CHL);
    const float sc = expf(mm[i]);
    float S = bb[i] * sc, Sv = aa[i] * sc;
#pragma unroll
    for (int j = 0; j < NCH; ++j) {
      sSk[j][lane] = S;
      sSkv[j][lane] = Sv;
      if (j < NCH - 1) {
        S = d64 * S + sBk[j][lane];
        Sv = d64 * Sv + sBkv[j][lane];
      }
    }
  }
  __syncthreads();

  float S = sSk[wid][lane], Sv = sSkv[wid][lane];
  size_t off = base + (size_t)t0 * CC;
#pragma unroll 4
  for (int t = t0; t < t1; ++t, off += CC) {
    float kk = __half2float(ek[off]);
    float vv = __bfloat162float(v[off]);
    float rv = __bfloat162float(r[off]);
    float kv = kk * vv;
    float wk = ef * kk + S;
    float wkv = ef * kv + Sv;
    S = d * S + kk;
    Sv = d * Sv + kv;
    float ratio = wkv / wk;
    if (isnan(ratio)) ratio = 0.0f;
    else if (isinf(ratio)) ratio = ratio > 0.0f ? FLT_MAX : -FLT_MAX;
    float sig = 1.0f / (1.0f + expf(-rv));
    rwkv[off] = __float2bfloat16(sig * ratio);
  }
}

extern "C" void kernel_launch(void* const* d_in, const int* in_sizes, int n_in,
                              void* d_out, int out_size, void* d_ws, size_t ws_size,
                              hipStream_t stream) {
  const float* x    = (const float*)d_in[0];
  const float* tdec = (const float*)d_in[1];
  const float* tfir = (const float*)d_in[2];
  const float* tmix = (const float*)d_in[3];
  const float* Wk   = (const float*)d_in[4];
  const float* Wv   = (const float*)d_in[5];
  const float* Wr   = (const float*)d_in[6];
  const float* Wo   = (const float*)d_in[7];
  const float* xx   = (const float*)d_in[8];
  const float* aa   = (const float*)d_in[9];
  const float* bb   = (const float*)d_in[10];
  const float* mm   = (const float*)d_in[11];

  char* ws = (char*)d_ws;
  size_t o = 0;
  __hip_bfloat16* W3  = (__hip_bfloat16*)(ws + o); o += (size_t)N3 * CC * 2;
  __hip_bfloat16* WoB = (__hip_bfloat16*)(ws + o); o += (size_t)CC * CC * 2;
  __hip_bfloat16* xmB = (__hip_bfloat16*)(ws + o); o += (size_t)MP * CC * 2;
  __hip_bfloat16* vB  = (__hip_bfloat16*)(ws + o); o += (size_t)MP * CC * 2;
  __hip_bfloat16* rB  = (__hip_bfloat16*)(ws + o); o += (size_t)MP * CC * 2;

  __half* ekH = (__half*)d_out;        // exp(k) fp16 lives in d_out until GEMM2
  __hip_bfloat16* rwkvB = xmB;         // rwkv reuses xm buffer (xm dead after GEMM1)

  prep<<<MP + CC * CC / 1024, 256, 0, stream>>>(x, xx, tmix, Wk, Wv, Wr, Wo,
                                                xmB, W3, WoB);
  gemm256<1><<<dim3(N3 / 256, MP / 256), 1024, 0, stream>>>(
      (const short*)xmB, (const short*)W3, nullptr, ekH, vB, rB);
  scan_fuse2<<<dim3(CC / 64, BB), 1024, 0, stream>>>(ekH, vB, rB, aa, bb, mm,
                                                     tdec, tfir, rwkvB);
  gemm256<0><<<dim3(CC / 256, MP / 256), 1024, 0, stream>>>(
      (const short*)rwkvB, (const short*)WoB, (float*)d_out, nullptr, nullptr, nullptr);
}